// Round 3
// baseline (142.478 us; speedup 1.0000x reference)
//
#include <hip/hip_runtime.h>

#define NRAYS 8192
#define NS    256
#define HID   64
#define RPB   4      // rays per block, one per wave

typedef float v2f __attribute__((ext_vector_type(2)));

static __device__ __forceinline__ float rdlane(float v, int l) {
    return __uint_as_float(__builtin_amdgcn_readlane(__float_as_uint(v), l));
}
static __device__ __forceinline__ v2f splat2(float s) { v2f v; v.x = s; v.y = s; return v; }

__global__ __launch_bounds__(256) void vr_kernel(
    const float* __restrict__ ray_start,
    const float* __restrict__ ray_dir,
    const float* __restrict__ sampled_depth,
    const float* __restrict__ sampled_dists,
    const int*   __restrict__ sampled_idx,
    const float* __restrict__ W1,
    const float* __restrict__ b1,
    const float* __restrict__ w_sigma,
    const float* __restrict__ W_rgb,
    const float* __restrict__ W_dir,
    const float* __restrict__ b_rgb,
    float* __restrict__ out)
{
    const int t    = threadIdx.x;
    const int lane = t & 63;
    const int wave = t >> 6;
    const int ray  = blockIdx.x * RPB + wave;

    const float ox = ray_start[ray*3+0], oy = ray_start[ray*3+1], oz = ray_start[ray*3+2];
    const float dx = ray_dir[ray*3+0],  dy = ray_dir[ray*3+1],  dz = ray_dir[ray*3+2];

    // per-ray view-dependent rgb bias (wave-uniform)
    const float dwr = dx*W_dir[0] + dy*W_dir[3] + dz*W_dir[6] + b_rgb[0];
    const float dwg = dx*W_dir[1] + dy*W_dir[4] + dz*W_dir[7] + b_rgb[1];
    const float dwb = dx*W_dir[2] + dy*W_dir[5] + dz*W_dir[8] + b_rgb[2];

    // Lane h holds hidden unit h's constants:
    //   hv(h, d) = relu(A[h] + d * B[h])
    const float w0 = W1[lane], w1 = W1[HID + lane], w2 = W1[2*HID + lane];
    const float Av = fmaf(w0, ox, fmaf(w1, oy, fmaf(w2, oz, b1[lane])));
    const float Bv = fmaf(w0, dx, fmaf(w1, dy, w2*dz));
    const float sv = w_sigma[lane];
    const float rv = W_rgb[lane*3+0], gv = W_rgb[lane*3+1], bv = W_rgb[lane*3+2];

    // this thread owns samples 4*lane .. 4*lane+3
    const size_t rbase = (size_t)ray * NS;
    const float4 dep = ((const float4*)(sampled_depth + rbase))[lane];
    const float4 dst = ((const float4*)(sampled_dists + rbase))[lane];
    const int4  vidx = ((const int4*)(sampled_idx + rbase))[lane];

    v2f d01; d01.x = dep.x; d01.y = dep.y;
    v2f d23; d23.x = dep.z; d23.y = dep.w;

    const v2f zero2 = splat2(0.f);
    v2f sig01 = zero2, sig23 = zero2;
    v2f cr01  = zero2, cr23  = zero2;
    v2f cg01  = zero2, cg23  = zero2;
    v2f cb01  = zero2, cb23  = zero2;

#pragma unroll
    for (int h = 0; h < HID; ++h) {
        const v2f a2 = splat2(rdlane(Av, h));
        const v2f b2 = splat2(rdlane(Bv, h));
        const v2f s2 = splat2(rdlane(sv, h));
        const v2f r2 = splat2(rdlane(rv, h));
        const v2f g2 = splat2(rdlane(gv, h));
        const v2f q2 = splat2(rdlane(bv, h));

        v2f h01 = __builtin_elementwise_fma(d01, b2, a2);
        v2f h23 = __builtin_elementwise_fma(d23, b2, a2);
        h01 = __builtin_elementwise_max(h01, zero2);   // relu
        h23 = __builtin_elementwise_max(h23, zero2);

        sig01 = __builtin_elementwise_fma(h01, s2, sig01);
        sig23 = __builtin_elementwise_fma(h23, s2, sig23);
        cr01  = __builtin_elementwise_fma(h01, r2, cr01);
        cr23  = __builtin_elementwise_fma(h23, r2, cr23);
        cg01  = __builtin_elementwise_fma(h01, g2, cg01);
        cg23  = __builtin_elementwise_fma(h23, g2, cg23);
        cb01  = __builtin_elementwise_fma(h01, q2, cb01);
        cb23  = __builtin_elementwise_fma(h23, q2, cb23);
    }

    const float sig[4] = {sig01.x, sig01.y, sig23.x, sig23.y};
    const float cr[4]  = {cr01.x,  cr01.y,  cr23.x,  cr23.y};
    const float cg[4]  = {cg01.x,  cg01.y,  cg23.x,  cg23.y};
    const float cb[4]  = {cb01.x,  cb01.y,  cb23.x,  cb23.y};
    const float dpt[4] = {dep.x, dep.y, dep.z, dep.w};
    const float dsv[4] = {dst.x, dst.y, dst.z, dst.w};
    const int  idx4[4] = {vidx.x, vidx.y, vidx.z, vidx.w};

    // free energy + thread-local inclusive scan
    float fe[4], c[4];
#pragma unroll
    for (int j = 0; j < 4; ++j) {
        float f = fmaxf(sig[j], 0.f) * dsv[j] * 7.0f;
        if (idx4[j] == -1) f = 0.f;
        fe[j] = f;
        c[j] = (j == 0) ? f : c[j-1] + f;
    }

    // wave-level exclusive scan of per-thread totals
    float tot = c[3];
#pragma unroll
    for (int off = 1; off < 64; off <<= 1) {
        float v = __shfl_up(tot, off, 64);
        if (lane >= off) tot += v;
    }
    const float base = tot - c[3];

    float s0 = 0.f, s1 = 0.f, s2 = 0.f, s3 = 0.f, s4 = 0.f;
    float prob[4];
#pragma unroll
    for (int j = 0; j < 4; ++j) {
        const float excl = base + ((j == 0) ? 0.f : c[j-1]);
        const float p = (1.f - __expf(-fe[j])) * __expf(-excl);
        prob[j] = p;
        const float r = __builtin_amdgcn_rcpf(1.f + __expf(-(cr[j] + dwr)));
        const float g = __builtin_amdgcn_rcpf(1.f + __expf(-(cg[j] + dwg)));
        const float b = __builtin_amdgcn_rcpf(1.f + __expf(-(cb[j] + dwb)));
        s0 += p;
        s1 = fmaf(dpt[j], p, s1);
        s2 = fmaf(r, p, s2);
        s3 = fmaf(g, p, s3);
        s4 = fmaf(b, p, s4);
    }

    // wave reduction of the 5 sums
#pragma unroll
    for (int off = 32; off >= 1; off >>= 1) {
        s0 += __shfl_xor(s0, off, 64);
        s1 += __shfl_xor(s1, off, 64);
        s2 += __shfl_xor(s2, off, 64);
        s3 += __shfl_xor(s3, off, 64);
        s4 += __shfl_xor(s4, off, 64);
    }

    float* orow = out + (size_t)ray * (NS + 5);
#pragma unroll
    for (int j = 0; j < 4; ++j)
        orow[5 + 4*lane + j] = prob[j];

    if (lane == 0) {
        orow[0] = s2;          // r
        orow[1] = s3;          // g
        orow[2] = s4;          // b
        orow[3] = s1;          // depth
        orow[4] = 1.f - s0;    // missed
    }
}

extern "C" void kernel_launch(void* const* d_in, const int* in_sizes, int n_in,
                              void* d_out, int out_size, void* d_ws, size_t ws_size,
                              hipStream_t stream)
{
    vr_kernel<<<NRAYS / RPB, 256, 0, stream>>>(
        (const float*)d_in[0],   // ray_start
        (const float*)d_in[1],   // ray_dir
        (const float*)d_in[2],   // sampled_depth
        (const float*)d_in[3],   // sampled_dists
        (const int*)  d_in[4],   // sampled_idx
        (const float*)d_in[5],   // W1
        (const float*)d_in[6],   // b1
        (const float*)d_in[7],   // w_sigma
        (const float*)d_in[8],   // W_rgb
        (const float*)d_in[9],   // W_dir
        (const float*)d_in[10],  // b_rgb
        (float*)d_out);
}

// Round 4
// 108.450 us; speedup vs baseline: 1.3138x; 1.3138x over previous
//
#include <hip/hip_runtime.h>

#define NRAYS 8192
#define NS    256
#define HID   64
#define RPB   8      // rays per block: 4 waves x 2 half-waves
#define SPT   8      // samples per thread (32 threads cover 256 samples)

__global__ __launch_bounds__(256) void vr_kernel(
    const float* __restrict__ ray_start,
    const float* __restrict__ ray_dir,
    const float* __restrict__ sampled_depth,
    const float* __restrict__ sampled_dists,
    const int*   __restrict__ sampled_idx,
    const float* __restrict__ W1,
    const float* __restrict__ b1,
    const float* __restrict__ w_sigma,
    const float* __restrict__ W_rgb,
    const float* __restrict__ W_dir,
    const float* __restrict__ b_rgb,
    float* __restrict__ out)
{
    // sW[h]     = {w_sigma[h], W_rgb[h][0], W_rgb[h][1], W_rgb[h][2]}  (block-shared)
    // sAB[r][h] = {A, B} with hv(h,d) = relu(A + d*B)                  (per-ray)
    __shared__ float4 sW[HID];
    __shared__ float2 sAB[RPB][HID];

    const int t = threadIdx.x;
    if (t < HID)
        sW[t] = make_float4(w_sigma[t], W_rgb[t*3+0], W_rgb[t*3+1], W_rgb[t*3+2]);

#pragma unroll
    for (int p = 0; p < 2; ++p) {
        const int idx = t + p * 256;        // 512 (ray,h) pairs
        const int r   = idx >> 6;
        const int h   = idx & 63;
        const int ray = blockIdx.x * RPB + r;
        const float ox = ray_start[ray*3+0], oy = ray_start[ray*3+1], oz = ray_start[ray*3+2];
        const float dx = ray_dir[ray*3+0],  dy = ray_dir[ray*3+1],  dz = ray_dir[ray*3+2];
        const float w0 = W1[h], w1 = W1[HID + h], w2 = W1[2*HID + h];
        const float A = fmaf(w0, ox, fmaf(w1, oy, fmaf(w2, oz, b1[h])));
        const float B = fmaf(w0, dx, fmaf(w1, dy, w2 * dz));
        sAB[r][h] = make_float2(A, B);
    }
    __syncthreads();

    const int lane = t & 63;
    const int wave = t >> 6;
    const int hl   = lane & 31;                 // position within half-wave
    const int r    = wave * 2 + (lane >> 5);    // ray slot in block
    const int ray  = blockIdx.x * RPB + r;

    // per-ray view-dependent rgb bias (W_dir/b_rgb are grid-uniform -> s_load)
    const float dx = ray_dir[ray*3+0], dy = ray_dir[ray*3+1], dz = ray_dir[ray*3+2];
    const float dwr = fmaf(dx, W_dir[0], fmaf(dy, W_dir[3], fmaf(dz, W_dir[6], b_rgb[0])));
    const float dwg = fmaf(dx, W_dir[1], fmaf(dy, W_dir[4], fmaf(dz, W_dir[7], b_rgb[1])));
    const float dwb = fmaf(dx, W_dir[2], fmaf(dy, W_dir[5], fmaf(dz, W_dir[8], b_rgb[2])));

    // this thread owns samples SPT*hl .. SPT*hl+7 (contiguous)
    const size_t rbase = (size_t)ray * NS + (size_t)hl * SPT;
    const float4 dep0 = ((const float4*)(sampled_depth + rbase))[0];
    const float4 dep1 = ((const float4*)(sampled_depth + rbase))[1];
    const float4 dst0 = ((const float4*)(sampled_dists + rbase))[0];
    const float4 dst1 = ((const float4*)(sampled_dists + rbase))[1];
    const int4   vi0  = ((const int4*)(sampled_idx + rbase))[0];
    const int4   vi1  = ((const int4*)(sampled_idx + rbase))[1];

    const float dpt[SPT] = {dep0.x, dep0.y, dep0.z, dep0.w, dep1.x, dep1.y, dep1.z, dep1.w};
    const float dsv[SPT] = {dst0.x, dst0.y, dst0.z, dst0.w, dst1.x, dst1.y, dst1.z, dst1.w};
    const int   vid[SPT] = {vi0.x, vi0.y, vi0.z, vi0.w, vi1.x, vi1.y, vi1.z, vi1.w};

    float sig[SPT] = {0,0,0,0,0,0,0,0};
    float cr[SPT]  = {0,0,0,0,0,0,0,0};
    float cg[SPT]  = {0,0,0,0,0,0,0,0};
    float cb[SPT]  = {0,0,0,0,0,0,0,0};

#pragma unroll 8
    for (int h = 0; h < HID; ++h) {
        const float4 w  = sW[h];
        const float2 ab = sAB[r][h];
#pragma unroll
        for (int j = 0; j < SPT; ++j) {
            const float hv = fmaxf(fmaf(ab.y, dpt[j], ab.x), 0.f);
            sig[j] = fmaf(hv, w.x, sig[j]);
            cr[j]  = fmaf(hv, w.y, cr[j]);
            cg[j]  = fmaf(hv, w.z, cg[j]);
            cb[j]  = fmaf(hv, w.w, cb[j]);
        }
    }

    // free energy + thread-local inclusive scan
    float c[SPT];
    float run = 0.f;
#pragma unroll
    for (int j = 0; j < SPT; ++j) {
        float f = fmaxf(sig[j], 0.f) * dsv[j] * 7.0f;
        if (vid[j] == -1) f = 0.f;
        run += f;
        c[j] = run;
    }

    // half-wave (width 32) exclusive scan of per-thread totals
    float tot = run;
#pragma unroll
    for (int off = 1; off < 32; off <<= 1) {
        const float v = __shfl_up(tot, off, 32);
        if (hl >= off) tot += v;
    }
    const float base = tot - run;   // exclusive prefix for this thread's first sample

    // probs via telescoping: p[j] = exp(-(base+c[j-1])) - exp(-(base+c[j]))
    float Eprev = __expf(-base);
    float prob[SPT];
    float s0 = 0.f, s1 = 0.f, s2 = 0.f, s3 = 0.f, s4 = 0.f;
#pragma unroll
    for (int j = 0; j < SPT; ++j) {
        const float Ej = __expf(-(base + c[j]));
        const float p  = Eprev - Ej;
        Eprev = Ej;
        prob[j] = p;
        const float rr = __builtin_amdgcn_rcpf(1.f + __expf(-(cr[j] + dwr)));
        const float gg = __builtin_amdgcn_rcpf(1.f + __expf(-(cg[j] + dwg)));
        const float bb = __builtin_amdgcn_rcpf(1.f + __expf(-(cb[j] + dwb)));
        s0 += p;
        s1 = fmaf(dpt[j], p, s1);
        s2 = fmaf(rr, p, s2);
        s3 = fmaf(gg, p, s3);
        s4 = fmaf(bb, p, s4);
    }

    // half-wave reduction of the 5 sums
#pragma unroll
    for (int off = 16; off >= 1; off >>= 1) {
        s0 += __shfl_xor(s0, off, 32);
        s1 += __shfl_xor(s1, off, 32);
        s2 += __shfl_xor(s2, off, 32);
        s3 += __shfl_xor(s3, off, 32);
        s4 += __shfl_xor(s4, off, 32);
    }

    float* orow = out + (size_t)ray * (NS + 5);
#pragma unroll
    for (int j = 0; j < SPT; ++j)
        orow[5 + SPT*hl + j] = prob[j];

    if (hl == 0) {
        orow[0] = s2;          // r
        orow[1] = s3;          // g
        orow[2] = s4;          // b
        orow[3] = s1;          // depth
        orow[4] = 1.f - s0;    // missed
    }
}

extern "C" void kernel_launch(void* const* d_in, const int* in_sizes, int n_in,
                              void* d_out, int out_size, void* d_ws, size_t ws_size,
                              hipStream_t stream)
{
    vr_kernel<<<NRAYS / RPB, 256, 0, stream>>>(
        (const float*)d_in[0],   // ray_start
        (const float*)d_in[1],   // ray_dir
        (const float*)d_in[2],   // sampled_depth
        (const float*)d_in[3],   // sampled_dists
        (const int*)  d_in[4],   // sampled_idx
        (const float*)d_in[5],   // W1
        (const float*)d_in[6],   // b1
        (const float*)d_in[7],   // w_sigma
        (const float*)d_in[8],   // W_rgb
        (const float*)d_in[9],   // W_dir
        (const float*)d_in[10],  // b_rgb
        (float*)d_out);
}